// Round 3
// baseline (713.272 us; speedup 1.0000x reference)
//
#include <hip/hip_runtime.h>
#include <hip/hip_bf16.h>
#include <cstdint>

#define B_DIM 4096
#define H_DIM 2048
#define I_DIM 2048
#define K_DIM 4096   // combined = H + I
#define N4    8192   // 4 * H

typedef unsigned int u32;
typedef unsigned short u16;
typedef __attribute__((ext_vector_type(4))) float floatx4;
typedef __attribute__((ext_vector_type(8))) short bf16x8;
typedef __attribute__((ext_vector_type(8))) float f32x8;
typedef __attribute__((ext_vector_type(8))) __bf16 bfx8;

__device__ static inline void gload16(const void* g, void* l) {
    __builtin_amdgcn_global_load_lds(
        (const __attribute__((address_space(1))) u32*)g,
        (__attribute__((address_space(3))) u32*)l, 16, 0, 0);
}
__device__ static inline float fast_sig(float x) {
    return 1.f / (1.f + __expf(-x));
}
__device__ static inline float fast_tanh(float x) {
    float ax = fabsf(x);
    float t = __expf(-2.f * ax);
    float r = (1.f - t) / (1.f + t);
    return copysignf(r, x);
}
// 8 f32 -> bf16x8 via v_cvt_pk_bf16_f32 (RNE; same numerics as prior rounds).
__device__ static inline bf16x8 pack8(float4 lo, float4 hi) {
    f32x8 t = { lo.x, lo.y, lo.z, lo.w, hi.x, hi.y, hi.z, hi.w };
    bfx8 b = __builtin_convertvector(t, bfx8);
    bf16x8 rr;
    __builtin_memcpy(&rr, &b, sizeof(rr));
    return rr;
}

// ---------------------------------------------------------------------------
// R3: single-kernel fused LSTM.  The separate fp32->bf16 convert pre-pass
// (~210us, structure-invariant across 3 variants => stop optimizing it) is
// ELIMINATED: the GEMM stages h_prev/x_t and the four W arrays DIRECTLY in
// f32 via global_load_lds, converting to bf16 at fragment-load time.
//   - gate-permute map moves into the per-lane GLOBAL source address
//     (gload_lds src is per-lane; dest stays linear -- rule #21)
//   - f32 tile row = 128B = 8 x 16B slots; swizzle slot u at row r holds
//     source k-chunk u^(r&7); read slot (2*quad+kk)^(r&7).  8 lanes/slot
//     balanced => conflict-free b128 (same argument as R1's measured-0).
//   - ring-2 LDS (128KiB), stage(t+1) issued right after barrier(t), wait
//     vmcnt(0) at TOP of body t+1 -- a full body (~2700cy) after issue, so
//     the drain is cheap (unlike m97's same-body drain).
//   - R1 body structure restored (R2's frag double-buffer regressed: the
//     compiler's fine-grained lgkmcnt already overlaps ds_read with MFMA).
//   - T1 XCD swizzle: 512 blocks, 8|512; each XCD's 32 resident CUs share
//     one 4MB A-panel (= L2 size).
// Race proof: stage(t+1) (post-barrier t) overwrites tile (t-1)'s buffer;
// every wave's frag reads of t-1 completed before its MFMAs(t-1) issued
// (compiler lgkm), which precede its arrival at barrier(t).
// ---------------------------------------------------------------------------
#define STAGE(T, NA, NB)                                                        \
  { _Pragma("unroll") for (int s_ = 0; s_ < 4; ++s_) {                          \
      const float* sa_ = (((T) < 64) ? h_prev : xmh) + aoff[s_] + (T) * 32;     \
      gload16(sa_, (char*)(NA) + (tid + s_ * 512) * 16);                        \
      gload16(bptr[s_] + (T) * 32, (char*)(NB) + (tid + s_ * 512) * 16);        \
  } }

#define BODY(T, CA, CB, NA, NB)                                                 \
  {                                                                             \
    asm volatile("s_waitcnt vmcnt(0)" ::: "memory");                            \
    __builtin_amdgcn_s_barrier();                                               \
    __builtin_amdgcn_sched_barrier(0);                                          \
    if ((T) + 1 < 128) STAGE((T) + 1, NA, NB);                                  \
    bf16x8 af_[8], bb_[4];                                                      \
    _Pragma("unroll") for (int i_ = 0; i_ < 8; ++i_) {                          \
      const float* pa_ = (CA) + (wm2 + i_ * 16 + r) * 32;                       \
      af_[i_] = pack8(*(const float4*)(pa_ + s0q), *(const float4*)(pa_ + s1q)); \
    }                                                                           \
    _Pragma("unroll") for (int g_ = 0; g_ < 4; ++g_) {                          \
      const float* pb_ = (CB) + (wn2 + g_ * 16 + r) * 32;                       \
      bb_[g_] = pack8(*(const float4*)(pb_ + s0q), *(const float4*)(pb_ + s1q)); \
    }                                                                           \
    __builtin_amdgcn_s_setprio(1);                                              \
    _Pragma("unroll") for (int i_ = 0; i_ < 8; ++i_)                            \
      _Pragma("unroll") for (int g_ = 0; g_ < 4; ++g_)                          \
        acc[i_][g_] = __builtin_amdgcn_mfma_f32_16x16x32_bf16(                  \
            af_[i_], bb_[g_], acc[i_][g_], 0, 0, 0);                            \
    __builtin_amdgcn_s_setprio(0);                                              \
  }

__global__ __launch_bounds__(512, 2) void gemm_lstm(
        const float* __restrict__ x_t, const float* __restrict__ h_prev,
        const float* __restrict__ c_prev,
        const float* __restrict__ Wf, const float* __restrict__ Wi,
        const float* __restrict__ Wc, const float* __restrict__ Wo,
        const float* __restrict__ bf_, const float* __restrict__ bi_,
        const float* __restrict__ bc_, const float* __restrict__ bo_,
        float* __restrict__ out) {
    __shared__ __align__(16) float lsA0[256 * 32];   // 32 KiB each
    __shared__ __align__(16) float lsB0[256 * 32];
    __shared__ __align__(16) float lsA1[256 * 32];
    __shared__ __align__(16) float lsB1[256 * 32];

    const int tid  = threadIdx.x;
    const int lane = tid & 63;
    const int wave = tid >> 6;
    const int wm2  = (wave >> 2) * 128;   // M half
    const int wn2  = (wave & 3) * 64;     // N quarter
    const int quad = lane >> 4;           // 0..3 (k-slice)
    const int r    = lane & 15;
    const int rx   = r & 7;
    const int s0q  = ((2 * quad)     ^ rx) * 4;  // f32 offset of lo 16B slot
    const int s1q  = ((2 * quad + 1) ^ rx) * 4;  // f32 offset of hi 16B slot

    // T1: XCD-aware block swizzle (512 blocks, 8 | 512 -> simple bijection).
    const int lin = blockIdx.y * gridDim.x + blockIdx.x;
    const int swz = (lin & 7) * 64 + (lin >> 3);
    const int bx  = swz & 31;             // wb-row tile  (N)
    const int by  = swz >> 5;             // batch tile   (M)
    const int mb  = by * 256;
    const int nbT = bx * 256;

    // Per-thread staging addresses.  Chunk c = tid + s*512: row = c>>3,
    // LDS slot u = c&7 holds source k-chunk u^(row&7)  (swizzle involution).
    int aoff[4];
    const float* bptr[4];
#pragma unroll
    for (int s = 0; s < 4; ++s) {
        int c   = tid + s * 512;
        int row = c >> 3;
        int sw  = ((c & 7) ^ (row & 7)) * 4;
        aoff[s] = (mb + row) * H_DIM + sw;           // h/x row stride 2048
        int n      = nbT + row;                      // GATE-PERMUTED B row
        int row128 = n & 127;
        int g      = (row128 >> 4) & 3;
        int j      = (n >> 7) * 32 + ((row128 >> 6) << 4) + (row128 & 15);
        const float* W = (g == 0) ? Wf : (g == 1) ? Wi : (g == 2) ? Wc : Wo;
        bptr[s] = W + (size_t)j * K_DIM + sw;
    }
    const float* xmh = x_t - H_DIM;   // (xmh + aoff + T*32) = x col T*32-2048

    floatx4 acc[8][4];
#pragma unroll
    for (int i = 0; i < 8; ++i)
#pragma unroll
        for (int g = 0; g < 4; ++g)
            acc[i][g] = (floatx4){0.f, 0.f, 0.f, 0.f};

    // Prologue: stage tile 0.
    STAGE(0, lsA0, lsB0);

#pragma unroll 1
    for (int t = 0; t < 128; t += 2) {
        BODY(t,     lsA0, lsB0, lsA1, lsB1);
        BODY(t + 1, lsA1, lsB1, lsA0, lsB0);
    }

    // Fence: keep epilogue-only state out of the K-loop's live range.
    __builtin_amdgcn_sched_barrier(0);

    // In-register LSTM epilogue.
    // C/D layout: col = lane&15, row = quad*4 + reg.  Gate-permuted staging
    // gives frag g = gate g of j = bx*64 + (wave&3)*16 + r (verified all 4
    // wn2 quarters against the n->(g,j) map).
    const int j = bx * 64 + (wave & 3) * 16 + r;
    const float bfv = bf_[j], biv = bi_[j], bcv = bc_[j], bov = bo_[j];
    const int rowb = mb + wm2 + quad * 4;
    const float* cp = c_prev + (size_t)rowb * H_DIM + j;
    float* oh = out + (size_t)rowb * H_DIM + j;
    float* oc = oh + (size_t)B_DIM * H_DIM;
#pragma unroll
    for (int i = 0; i < 8; ++i) {
#pragma unroll
        for (int rg = 0; rg < 4; ++rg) {
            size_t off = (size_t)(i * 16 + rg) * H_DIM;
            float gf = acc[i][0][rg] + bfv;
            float gi = acc[i][1][rg] + biv;
            float gc = acc[i][2][rg] + bcv;
            float go = acc[i][3][rg] + bov;
            float f  = fast_sig(gf);
            float ii = fast_sig(gi);
            float ct = fast_tanh(gc);
            float oo = fast_sig(go);
            float c  = f * cp[off] + ii * ct;
            float h  = oo * fast_tanh(c);
            oh[off] = h;
            oc[off] = c;
        }
    }
}

extern "C" void kernel_launch(void* const* d_in, const int* in_sizes, int n_in,
                              void* d_out, int out_size, void* d_ws, size_t ws_size,
                              hipStream_t stream) {
    const float* x_t    = (const float*)d_in[0];
    const float* h_prev = (const float*)d_in[1];
    const float* c_prev = (const float*)d_in[2];
    const float* Wf = (const float*)d_in[3];  const float* bf_ = (const float*)d_in[4];
    const float* Wi = (const float*)d_in[5];  const float* bi_ = (const float*)d_in[6];
    const float* Wc = (const float*)d_in[7];  const float* bc_ = (const float*)d_in[8];
    const float* Wo = (const float*)d_in[9];  const float* bo_ = (const float*)d_in[10];
    float* out = (float*)d_out;

    dim3 grid(N4 / 256, B_DIM / 256);  // (32, 16) = 512 blocks
    gemm_lstm<<<grid, 512, 0, stream>>>(x_t, h_prev, c_prev,
                                        Wf, Wi, Wc, Wo,
                                        bf_, bi_, bc_, bo_, out);
}

// Round 4
// 547.388 us; speedup vs baseline: 1.3030x; 1.3030x over previous
//
#include <hip/hip_runtime.h>
#include <hip/hip_bf16.h>
#include <cstdint>

#define B_DIM 4096
#define H_DIM 2048
#define I_DIM 2048
#define K_DIM 4096   // combined = H + I
#define N4    8192   // 4 * H

typedef unsigned int u32;
typedef unsigned short u16;
typedef __attribute__((ext_vector_type(4))) float floatx4;
typedef __attribute__((ext_vector_type(8))) short bf16x8;
typedef __attribute__((ext_vector_type(8))) float f32x8;
typedef __attribute__((ext_vector_type(8))) __bf16 bfx8;

__device__ static inline void gload16(const void* g, void* l) {
    __builtin_amdgcn_global_load_lds(
        (const __attribute__((address_space(1))) u32*)g,
        (__attribute__((address_space(3))) u32*)l, 16, 0, 0);
}
__device__ static inline float fast_sig(float x) {
    return 1.f / (1.f + __expf(-x));
}
__device__ static inline float fast_tanh(float x) {
    float ax = fabsf(x);
    float t = __expf(-2.f * ax);
    float r = (1.f - t) / (1.f + t);
    return copysignf(r, x);
}

// ---------------------------------------------------------------------------
// Kernel 1: fp32 -> bf16 convert pre-pass (REVERTED to R1's exact version --
// R3's f32-direct GEMM was a 2x regression: f32 working set blew L3 (FETCH
// 215->1098 MB) and the 128B-row swizzle was conflict-broken (5e7)).
// R3 also showed total-minus-gemm has a ~95us fixed harness overhead, so this
// kernel really costs ~110us vs a 61us BW floor -- near-roofline, leave it.
//  blocks [0, 8192):       comb[4096][4096] = bf16(concat([h_prev, x_t], 1))
//  blocks [8192, 24576):   wb[8192][4096]   = bf16(W), GATE-PERMUTED rows:
//    wb row n  <-  W_g row j:  row128 = n & 127, g = (row128>>4)&3,
//                              j = (n>>7)*32 + ((row128>>6)<<4) + (row128&15)
// ---------------------------------------------------------------------------
__global__ void convert_all(const float* __restrict__ h_prev, const float* __restrict__ x_t,
                            const float* __restrict__ Wf, const float* __restrict__ Wi,
                            const float* __restrict__ Wc, const float* __restrict__ Wo,
                            u16* __restrict__ comb, u16* __restrict__ wb) {
    const int bid = blockIdx.x;
    const float* src;
    u16* dst;
    if (bid < 8192) {
        int base = (bid * 256 + (int)threadIdx.x) * 8;   // < 2^24
        int row = base >> 12, col = base & 4095;
        src = (col < H_DIM) ? h_prev + (size_t)row * H_DIM + col
                            : x_t    + (size_t)row * I_DIM + (col - H_DIM);
        dst = comb + base;
    } else {
        long long base = ((long long)(bid - 8192) * 256 + threadIdx.x) * 8;
        int n = (int)(base >> 12), col = (int)(base & 4095);
        int row128 = n & 127;
        int g = (row128 >> 4) & 3;
        int j = (n >> 7) * 32 + ((row128 >> 6) << 4) + (row128 & 15);
        const float* W = (g == 0) ? Wf : (g == 1) ? Wi : (g == 2) ? Wc : Wo;
        src = W + (size_t)j * K_DIM + col;
        dst = wb + base;
    }
    float4 v0 = *(const float4*)src;
    float4 v1 = *(const float4*)(src + 4);
    f32x8 f = { v0.x, v0.y, v0.z, v0.w, v1.x, v1.y, v1.z, v1.w };
    *(bfx8*)dst = __builtin_convertvector(f, bfx8);   // v_cvt_pk_bf16_f32 (RNE)
}

// ---------------------------------------------------------------------------
// Kernel 2: fused GEMM + LSTM epilogue.
// R4 CHANGE (single change vs R1's 285.8us/962TF version): split each K-tile
// body into TWO m201-granularity phases (16 MFMA per barrier-paced cluster)
// instead of one 32-MFMA body.  m201 evidence: this pacing -- reads issued
// pre-barrier, MFMA cluster post-barrier -- lets each phase's ds_reads
// execute while the previous phase's MFMAs drain, and is the structure that
// reaches 62-69% MfmaUtil at identical waves/SIMD (2) and MFMA/phase (16).
// All R1 memory machinery is UNCHANGED: BK=32, ring-4 LDS, stage lead 3,
// counted vmcnt(8), measured-0-conflict swizzle, same numerics/epilogue.
//   P0(t): vmcnt(8); barrier; [stage A(t+3)] afL+bb reads (8); MFMA i0-3.
//   P1(t): afH reads (4); [stage B(t+3)]; barrier; MFMA i4-7.
// Race proof (R1's, verbatim): all tile-(t-1) frag reads complete before
// each wave's MFMAs(t-1) issue (reg dep), which precede its arrival at
// P0(t)'s barrier; the overwrite of buf[(t-1)&3] = buf[(t+3)&3] is issued
// only after that barrier.  vmcnt(8) = 2 tiles x 4 loads/thread in flight
// => tile t fully resident at P0(t).  (t=125: 8 newest = tiles 126,127 ->
// still safe; t=126/127 drain with vmcnt(0).)
// ---------------------------------------------------------------------------
#define TILE(T, VMS, DOSTAGE)                                                   \
  {                                                                             \
    asm volatile("s_waitcnt vmcnt(" VMS ")" ::: "memory");                      \
    __builtin_amdgcn_s_barrier();                                               \
    __builtin_amdgcn_sched_barrier(0);                                          \
    const u16* sA_ = lsA[(T) & 3];                                              \
    const u16* sB_ = lsB[(T) & 3];                                              \
    if (DOSTAGE) {                                                              \
      const u16* as_ = aSrc + ((T) + 3) * 32;                                   \
      char* dA_ = (char*)lsA[((T) + 3) & 3] + doff;                             \
      gload16(as_, dA_);                                                        \
      gload16(as_ + 128 * K_DIM, dA_ + 8192);                                   \
    }                                                                           \
    bf16x8 afL_[4], afH_[4], bb_[4];                                            \
    _Pragma("unroll") for (int i_ = 0; i_ < 4; ++i_)                            \
      afL_[i_] = *(const bf16x8*)&sA_[(wm2 + i_ * 16 + r) * 32 + qsw];          \
    _Pragma("unroll") for (int g_ = 0; g_ < 4; ++g_)                            \
      bb_[g_] = *(const bf16x8*)&sB_[(wn2 + g_ * 16 + r) * 32 + qsw];           \
    __builtin_amdgcn_s_setprio(1);                                              \
    _Pragma("unroll") for (int i_ = 0; i_ < 4; ++i_)                            \
      _Pragma("unroll") for (int g_ = 0; g_ < 4; ++g_)                          \
        acc[i_][g_] = __builtin_amdgcn_mfma_f32_16x16x32_bf16(                  \
            afL_[i_], bb_[g_], acc[i_][g_], 0, 0, 0);                           \
    __builtin_amdgcn_s_setprio(0);                                              \
    _Pragma("unroll") for (int i_ = 0; i_ < 4; ++i_)                            \
      afH_[i_] = *(const bf16x8*)&sA_[(wm2 + 64 + i_ * 16 + r) * 32 + qsw];     \
    if (DOSTAGE) {                                                              \
      const u16* bs_ = bSrc + ((T) + 3) * 32;                                   \
      char* dB_ = (char*)lsB[((T) + 3) & 3] + doff;                             \
      gload16(bs_, dB_);                                                        \
      gload16(bs_ + 128 * K_DIM, dB_ + 8192);                                   \
    }                                                                           \
    __builtin_amdgcn_s_barrier();                                               \
    __builtin_amdgcn_sched_barrier(0);                                          \
    __builtin_amdgcn_s_setprio(1);                                              \
    _Pragma("unroll") for (int i_ = 0; i_ < 4; ++i_)                            \
      _Pragma("unroll") for (int g_ = 0; g_ < 4; ++g_)                          \
        acc[4 + i_][g_] = __builtin_amdgcn_mfma_f32_16x16x32_bf16(              \
            afH_[i_], bb_[g_], acc[4 + i_][g_], 0, 0, 0);                       \
    __builtin_amdgcn_s_setprio(0);                                              \
  }

__global__ __launch_bounds__(512, 2) void gemm_lstm(const u16* __restrict__ A,
                                                    const u16* __restrict__ Bm,
                                                    const float* __restrict__ c_prev,
                                                    const float* __restrict__ bf_,
                                                    const float* __restrict__ bi_,
                                                    const float* __restrict__ bc_,
                                                    const float* __restrict__ bo_,
                                                    float* __restrict__ out) {
    __shared__ __align__(16) u16 lsA[4][256 * 32];   // 64 KiB
    __shared__ __align__(16) u16 lsB[4][256 * 32];   // 64 KiB

    const int tid  = threadIdx.x;
    const int lane = tid & 63;
    const int wave = tid >> 6;
    const int wm2  = (wave >> 2) * 128;   // M half (0/128)
    const int wn2  = (wave & 3) * 64;     // N quarter
    const int quad = lane >> 4;           // 0..3 (k-slice)
    const int r    = lane & 15;           // 0..15
    const int qsw  = (quad ^ ((r >> 1) & 3)) * 8;   // swizzled k-chunk (elems)
    const int mb   = blockIdx.y * 256;    // batch tile
    const int nbT  = blockIdx.x * 256;    // wb row tile

    // Per-thread staging addresses (source column pre-swizzled; chunk tid and
    // tid+512 share the pattern since ((tid+512)>>3)&3 == (tid>>3)&3).
    const int ko = ((tid & 3) ^ ((tid >> 3) & 3)) * 8;
    const u16* aSrc = A  + (size_t)(mb  + (tid >> 2)) * K_DIM + ko;
    const u16* bSrc = Bm + (size_t)(nbT + (tid >> 2)) * K_DIM + ko;
    const int doff = tid * 16;

    floatx4 acc[8][4];
#pragma unroll
    for (int i = 0; i < 8; ++i)
#pragma unroll
        for (int g = 0; g < 4; ++g)
            acc[i][g] = (floatx4){0.f, 0.f, 0.f, 0.f};

    // Prologue: stage tiles 0,1,2 (A then B per tile; oldest-first order is
    // what the counted vmcnt(8) relies on).
#pragma unroll
    for (int pt = 0; pt < 3; ++pt) {
        const u16* as_ = aSrc + pt * 32;
        char* dA_ = (char*)lsA[pt] + doff;
        gload16(as_, dA_);
        gload16(as_ + 128 * K_DIM, dA_ + 8192);
        const u16* bs_ = bSrc + pt * 32;
        char* dB_ = (char*)lsB[pt] + doff;
        gload16(bs_, dB_);
        gload16(bs_ + 128 * K_DIM, dB_ + 8192);
    }

#pragma unroll 1
    for (int t = 0; t < 125; ++t) TILE(t, "8", 1);
    TILE(125, "8", 0);
    TILE(126, "0", 0);
    TILE(127, "0", 0);

    // Fence: keep epilogue-only state out of the K-loop's live range.
    __builtin_amdgcn_sched_barrier(0);

    // In-register LSTM epilogue.
    // C/D layout: col = lane&15, row = quad*4 + reg.  Gate-permuted wb gives
    // frag g = gate g of j = bx*64 + (wave&3)*16 + r.
    const int j = blockIdx.x * 64 + (wave & 3) * 16 + r;
    const float bfv = bf_[j], biv = bi_[j], bcv = bc_[j], bov = bo_[j];
    const int rowb = mb + wm2 + quad * 4;
    const float* cp = c_prev + (size_t)rowb * H_DIM + j;
    float* oh = out + (size_t)rowb * H_DIM + j;
    float* oc = oh + (size_t)B_DIM * H_DIM;
#pragma unroll
    for (int i = 0; i < 8; ++i) {
#pragma unroll
        for (int rg = 0; rg < 4; ++rg) {
            size_t off = (size_t)(i * 16 + rg) * H_DIM;
            float gf = acc[i][0][rg] + bfv;
            float gi = acc[i][1][rg] + biv;
            float gc = acc[i][2][rg] + bcv;
            float go = acc[i][3][rg] + bov;
            float f  = fast_sig(gf);
            float ii = fast_sig(gi);
            float ct = fast_tanh(gc);
            float oo = fast_sig(go);
            float c  = f * cp[off] + ii * ct;
            float h  = oo * fast_tanh(c);
            oh[off] = h;
            oc[off] = c;
        }
    }
}

// ---------------------------------------------------------------------------
// Fallback (only if ws_size < 96 MiB): naive fp32, correct but slow.
// ---------------------------------------------------------------------------
__global__ void lstm_naive(const float* __restrict__ x_t, const float* __restrict__ h_prev,
                           const float* __restrict__ c_prev,
                           const float* __restrict__ Wf, const float* __restrict__ bf_,
                           const float* __restrict__ Wi, const float* __restrict__ bi_,
                           const float* __restrict__ Wc, const float* __restrict__ bc_,
                           const float* __restrict__ Wo, const float* __restrict__ bo_,
                           float* __restrict__ out) {
    int j = blockIdx.x * blockDim.x + threadIdx.x;  // 0..2047
    int b = blockIdx.y;                             // 0..4095
    const float* hrow = h_prev + (long long)b * H_DIM;
    const float* xrow = x_t   + (long long)b * I_DIM;
    const float* wf = Wf + (long long)j * K_DIM;
    const float* wi = Wi + (long long)j * K_DIM;
    const float* wc = Wc + (long long)j * K_DIM;
    const float* wo = Wo + (long long)j * K_DIM;
    float af = bf_[j], ai = bi_[j], ac = bc_[j], ao = bo_[j];
    for (int k = 0; k < H_DIM; k += 4) {
        float4 v = *(const float4*)(hrow + k);
        float4 a = *(const float4*)(wf + k);
        float4 bqi = *(const float4*)(wi + k);
        float4 cq = *(const float4*)(wc + k);
        float4 dq = *(const float4*)(wo + k);
        af += v.x*a.x + v.y*a.y + v.z*a.z + v.w*a.w;
        ai += v.x*bqi.x + v.y*bqi.y + v.z*bqi.z + v.w*bqi.w;
        ac += v.x*cq.x + v.y*cq.y + v.z*cq.z + v.w*cq.w;
        ao += v.x*dq.x + v.y*dq.y + v.z*dq.z + v.w*dq.w;
    }
    for (int k = 0; k < I_DIM; k += 4) {
        float4 v = *(const float4*)(xrow + k);
        float4 a = *(const float4*)(wf + H_DIM + k);
        float4 bqi = *(const float4*)(wi + H_DIM + k);
        float4 cq = *(const float4*)(wc + H_DIM + k);
        float4 dq = *(const float4*)(wo + H_DIM + k);
        af += v.x*a.x + v.y*a.y + v.z*a.z + v.w*a.w;
        ai += v.x*bqi.x + v.y*bqi.y + v.z*bqi.z + v.w*bqi.w;
        ac += v.x*cq.x + v.y*cq.y + v.z*cq.z + v.w*cq.w;
        ao += v.x*dq.x + v.y*dq.y + v.z*dq.z + v.w*dq.w;
    }
    float f  = 1.f / (1.f + __expf(-af));
    float ii = 1.f / (1.f + __expf(-ai));
    float ct = tanhf(ac);
    float oo = 1.f / (1.f + __expf(-ao));
    int t = b * H_DIM + j;
    float c = f * c_prev[t] + ii * ct;
    out[t] = oo * tanhf(c);
    out[B_DIM * H_DIM + t] = c;
}

extern "C" void kernel_launch(void* const* d_in, const int* in_sizes, int n_in,
                              void* d_out, int out_size, void* d_ws, size_t ws_size,
                              hipStream_t stream) {
    const float* x_t    = (const float*)d_in[0];
    const float* h_prev = (const float*)d_in[1];
    const float* c_prev = (const float*)d_in[2];
    const float* Wf = (const float*)d_in[3];  const float* bf_ = (const float*)d_in[4];
    const float* Wi = (const float*)d_in[5];  const float* bi_ = (const float*)d_in[6];
    const float* Wc = (const float*)d_in[7];  const float* bc_ = (const float*)d_in[8];
    const float* Wo = (const float*)d_in[9];  const float* bo_ = (const float*)d_in[10];
    float* out = (float*)d_out;

    const size_t comb_elems = (size_t)B_DIM * K_DIM;   // 16.7M u16
    const size_t wb_elems   = (size_t)N4 * K_DIM;      // 33.5M u16
    const size_t need = (comb_elems + wb_elems) * sizeof(u16);  // 96 MiB

    if (ws_size >= need) {
        u16* comb = (u16*)d_ws;
        u16* wb   = comb + comb_elems;
        convert_all<<<24576, 256, 0, stream>>>(h_prev, x_t, Wf, Wi, Wc, Wo, comb, wb);
        dim3 grid(N4 / 256, B_DIM / 256);  // (32, 16)
        gemm_lstm<<<grid, 512, 0, stream>>>(comb, wb, c_prev, bf_, bi_, bc_, bo_, out);
    } else {
        dim3 grid(H_DIM / 256, B_DIM);
        lstm_naive<<<grid, 256, 0, stream>>>(x_t, h_prev, c_prev,
                                             Wf, bf_, Wi, bi_, Wc, bc_, Wo, bo_, out);
    }
}